// Round 5
// baseline (608.907 us; speedup 1.0000x reference)
//
#include <hip/hip_runtime.h>
#include <cstdint>

// ---------- types ----------
typedef __bf16 bf16;
typedef __bf16 bf16x8 __attribute__((ext_vector_type(8)));
typedef float  f32x4  __attribute__((ext_vector_type(4)));

#define AS1(p) ((__attribute__((address_space(1))) void*)(p))
#define AS3(p) ((__attribute__((address_space(3))) void*)(p))

__device__ __forceinline__ void gload16(const void* g, void* l) {
  __builtin_amdgcn_global_load_lds(AS1(g), AS3(l), 16, 0, 0);
}

// ---------- problem constants ----------
constexpr int B_ = 2, S_ = 2048, E_ = 4096, H_ = 32, KVH_ = 8, D_ = 128;
constexpr int QPK_ = H_ / KVH_;            // 4
constexpr int F_ = E_ + 2 * KVH_ * D_;     // 6144
constexpr int M_ = B_ * S_;                // 4096 rows of x

// ---------- fp32 -> bf16 convert (8 elems/thread) ----------
__global__ void f2bf_k(const float* __restrict__ in, bf16* __restrict__ out, int n8) {
  int i = blockIdx.x * 256 + threadIdx.x;
  if (i >= n8) return;
  const float4* p = (const float4*)(in + (size_t)i * 8);
  float4 a = p[0], b = p[1];
  bf16x8 o;
  o[0] = (bf16)a.x; o[1] = (bf16)a.y; o[2] = (bf16)a.z; o[3] = (bf16)a.w;
  o[4] = (bf16)b.x; o[5] = (bf16)b.y; o[6] = (bf16)b.z; o[7] = (bf16)b.w;
  *(bf16x8*)(out + (size_t)i * 8) = o;
}

// ---------- RoPE cos/sin table ----------
__global__ void rope_table_k(float2* __restrict__ tab) {
  int i = blockIdx.x * 256 + threadIdx.x;   // S_*64 = 131072
  int s = i >> 6, f = i & 63;
  float inv = powf(10000.0f, -2.0f * (float)f / 128.0f);
  float ang = (float)s * inv;
  tab[i] = make_float2(cosf(ang), sinf(ang));
}

// ---------- 256x256 8-phase bf16 GEMM, B^T input: C[M][N] = A[M][K]*B[N][K]^T ----
// 512 thr = 8 waves (2M x 4N); per-wave 128x64 out = acc[8][4]; BK=64; LDS 128KB
// dbuf. Swizzle: LDS[row][colb ^ ((row&7)<<4)] via pre-swizzled global source
// (linear gload_lds dest, rule 21) + swizzled ds_read. Counted vmcnt(4) per
// K-tile boundary (T4); raw barriers + clobber-free waits (r4: clobbered waits
// made the compiler drain everything -> m97 ceiling). XCD-chunked block swizzle
// (T1): same-XCD blocks share an A-panel (grids are %8 == 0 -> bijective).
template <typename OutT>
__global__ __launch_bounds__(512, 2)
void gemm256(const bf16* __restrict__ A, const bf16* __restrict__ B,
             OutT* __restrict__ C, int M, int N, int K) {
  __shared__ bf16 As[2][16384];   // [256 rows][64 el], 128B rows
  __shared__ bf16 Bs[2][16384];
  const int tid = threadIdx.x;
  const int wid = tid >> 6, lane = tid & 63;
  const int l15 = lane & 15, g = lane >> 4;
  const int wr = wid >> 2, wc = wid & 3;
  // XCD swizzle: consecutive dispatch ids round-robin XCDs; give each XCD a
  // contiguous chunk of tiles grouped by bm (A-panel L2 reuse).
  const int gx = gridDim.x, gy = gridDim.y;
  const int id = blockIdx.y * gx + blockIdx.x;
  const int cpx = (gx * gy) >> 3;
  const int swz = (id & 7) * cpx + (id >> 3);
  const int bm = swz / gy, bn = swz % gy;
  const bf16* Ab = A + (size_t)bm * 256 * K;
  const bf16* Bb = B + (size_t)bn * 256 * K;
  const int nT = K >> 6;
  const int swzr = (l15 & 7) << 4;   // read-side byte swizzle for row = *+l15

  f32x4 acc[8][4];
#pragma unroll
  for (int m = 0; m < 8; ++m)
#pragma unroll
    for (int n = 0; n < 4; ++n) acc[m][n] = (f32x4){0.f, 0.f, 0.f, 0.f};

  // stage half-tile h (rows h*128..+127) of K-tile t into dst (As[b]/Bs[b]).
  auto stg = [&](const bf16* src, bf16* dst, int t, int h) {
#pragma unroll
    for (int i = 0; i < 2; ++i) {
      int lb = h * 16384 + i * 8192 + wid * 1024 + lane * 16;  // byte off in tile
      int row = lb >> 7;
      int colb = (lb & 127) ^ ((row & 7) << 4);
      gload16(src + (size_t)row * K + t * 64 + (colb >> 1),
              dst + ((h * 16384 + i * 8192 + wid * 1024) >> 1));
    }
  };

  bf16x8 af[4][2];        // current mh-half A frags
  bf16x8 bfr[2][2][2];    // [nh][n][ks] B frags (all 8 live)

  // ---- prologue: t0 full + t1 B-halves; wait t0 landed (keep t1B in flight)
  stg(Bb, Bs[0], 0, 0); stg(Bb, Bs[0], 0, 1);
  stg(Ab, As[0], 0, 0); stg(Ab, As[0], 0, 1);
  if (nT > 1) {
    stg(Bb, Bs[1], 1, 0); stg(Bb, Bs[1], 1, 1);
    asm volatile("s_waitcnt vmcnt(4)");
  } else {
    asm volatile("s_waitcnt vmcnt(0)");
  }
  __builtin_amdgcn_sched_barrier(0);
  __builtin_amdgcn_s_barrier();

  for (int t = 0; t < nT; ++t) {
    const int cur = t & 1;
    // ---------------- P1: A-lo + B-lo reads; stage (t+1) A0 ----------------
#pragma unroll
    for (int m = 0; m < 4; ++m) {
      int arow = wr * 128 + m * 16 + l15;
#pragma unroll
      for (int ks = 0; ks < 2; ++ks)
        af[m][ks] = *(const bf16x8*)&As[cur][(arow << 6) + (((ks * 64 + g * 16) ^ swzr) >> 1)];
    }
#pragma unroll
    for (int n = 0; n < 2; ++n) {
      int brow = wc * 64 + n * 16 + l15;
#pragma unroll
      for (int ks = 0; ks < 2; ++ks)
        bfr[0][n][ks] = *(const bf16x8*)&Bs[cur][(brow << 6) + (((ks * 64 + g * 16) ^ swzr) >> 1)];
    }
    if (t + 1 < nT) stg(Ab, As[cur ^ 1], t + 1, 0);
    __builtin_amdgcn_s_barrier();
    asm volatile("s_waitcnt lgkmcnt(0)");
    __builtin_amdgcn_s_setprio(1);
#pragma unroll
    for (int ks = 0; ks < 2; ++ks)
#pragma unroll
      for (int m = 0; m < 4; ++m)
#pragma unroll
        for (int n = 0; n < 2; ++n)
          acc[m][n] = __builtin_amdgcn_mfma_f32_16x16x32_bf16(af[m][ks], bfr[0][n][ks], acc[m][n], 0, 0, 0);
    __builtin_amdgcn_s_setprio(0);
    __builtin_amdgcn_s_barrier();
    // ---------------- P2: B-hi reads; stage (t+1) A1 ----------------
#pragma unroll
    for (int n = 0; n < 2; ++n) {
      int brow = wc * 64 + 32 + n * 16 + l15;
#pragma unroll
      for (int ks = 0; ks < 2; ++ks)
        bfr[1][n][ks] = *(const bf16x8*)&Bs[cur][(brow << 6) + (((ks * 64 + g * 16) ^ swzr) >> 1)];
    }
    if (t + 1 < nT) stg(Ab, As[cur ^ 1], t + 1, 1);
    __builtin_amdgcn_s_barrier();
    asm volatile("s_waitcnt lgkmcnt(0)");
    __builtin_amdgcn_s_setprio(1);
#pragma unroll
    for (int ks = 0; ks < 2; ++ks)
#pragma unroll
      for (int m = 0; m < 4; ++m)
#pragma unroll
        for (int n = 0; n < 2; ++n)
          acc[m][2 + n] = __builtin_amdgcn_mfma_f32_16x16x32_bf16(af[m][ks], bfr[1][n][ks], acc[m][2 + n], 0, 0, 0);
    __builtin_amdgcn_s_setprio(0);
    __builtin_amdgcn_s_barrier();
    // ---------------- P3: A-hi reads; stage (t+2) B0 ----------------
#pragma unroll
    for (int m = 0; m < 4; ++m) {
      int arow = wr * 128 + 64 + m * 16 + l15;
#pragma unroll
      for (int ks = 0; ks < 2; ++ks)
        af[m][ks] = *(const bf16x8*)&As[cur][(arow << 6) + (((ks * 64 + g * 16) ^ swzr) >> 1)];
    }
    if (t + 2 < nT) stg(Bb, Bs[cur], t + 2, 0);
    __builtin_amdgcn_s_barrier();
    asm volatile("s_waitcnt lgkmcnt(0)");
    __builtin_amdgcn_s_setprio(1);
#pragma unroll
    for (int ks = 0; ks < 2; ++ks)
#pragma unroll
      for (int m = 0; m < 4; ++m)
#pragma unroll
        for (int n = 0; n < 2; ++n)
          acc[4 + m][n] = __builtin_amdgcn_mfma_f32_16x16x32_bf16(af[m][ks], bfr[0][n][ks], acc[4 + m][n], 0, 0, 0);
    __builtin_amdgcn_s_setprio(0);
    __builtin_amdgcn_s_barrier();
    // ---------------- P4: stage (t+2) B1; MFMA; counted boundary vmcnt -------
    if (t + 2 < nT) stg(Bb, Bs[cur], t + 2, 1);
    __builtin_amdgcn_s_setprio(1);
#pragma unroll
    for (int ks = 0; ks < 2; ++ks)
#pragma unroll
      for (int m = 0; m < 4; ++m)
#pragma unroll
        for (int n = 0; n < 2; ++n)
          acc[4 + m][2 + n] = __builtin_amdgcn_mfma_f32_16x16x32_bf16(af[m][ks], bfr[1][n][ks], acc[4 + m][2 + n], 0, 0, 0);
    __builtin_amdgcn_s_setprio(0);
    if (t + 2 < nT)      { asm volatile("s_waitcnt vmcnt(4)"); }
    else if (t + 1 < nT) { asm volatile("s_waitcnt vmcnt(0)"); }
    __builtin_amdgcn_sched_barrier(0);   // pin next-tile ds_reads below the wait
    __builtin_amdgcn_s_barrier();
  }

  // epilogue: C/D layout col=lane&15, row=(lane>>4)*4+r  [measured m89]
#pragma unroll
  for (int mh = 0; mh < 2; ++mh)
#pragma unroll
    for (int m = 0; m < 4; ++m) {
      int row0 = bm * 256 + wr * 128 + mh * 64 + m * 16 + g * 4;
#pragma unroll
      for (int nh = 0; nh < 2; ++nh)
#pragma unroll
        for (int n = 0; n < 2; ++n) {
          int col = bn * 256 + wc * 64 + nh * 32 + n * 16 + l15;
          f32x4 v = acc[mh * 4 + m][nh * 2 + n];
#pragma unroll
          for (int r = 0; r < 4; ++r)
            C[(size_t)(row0 + r) * N + col] = (OutT)v[r];
        }
    }
}

// ---------- RoPE on Q: qkv[M][F] -> q[B][S][H][D] (interleaved pairs) ----------
__global__ void rope_q_k(const bf16* __restrict__ qkv, const float2* __restrict__ tab,
                         bf16* __restrict__ qout) {
  int idx = blockIdx.x * 256 + threadIdx.x;  // B*S*H*16 = 2097152
  int c = idx & 15;
  int h = (idx >> 4) & 31;
  int s = (idx >> 9) & 2047;
  int b = idx >> 20;
  int d0 = c * 8;
  int kvh = h >> 2, j = h & 3;
  const bf16* src = qkv + (size_t)(b * 2048 + s) * F_ + kvh * (QPK_ + 2) * D_ + j * D_ + d0;
  bf16x8 v = *(const bf16x8*)src;
  const float2* tb = tab + s * 64 + (d0 >> 1);
  bf16x8 o;
#pragma unroll
  for (int p = 0; p < 4; ++p) {
    float x0 = (float)v[2 * p], x1 = (float)v[2 * p + 1];
    float2 cs = tb[p];
    o[2 * p]     = (bf16)(x0 * cs.x - x1 * cs.y);
    o[2 * p + 1] = (bf16)(x0 * cs.y + x1 * cs.x);
  }
  *(bf16x8*)(qout + (((size_t)b * 2048 + s) * 32 + h) * 128 + d0) = o;
}

// ---------- RoPE on K: qkv -> k[B][KVH][S][D] ----------
__global__ void rope_k_k(const bf16* __restrict__ qkv, const float2* __restrict__ tab,
                         bf16* __restrict__ kout) {
  int idx = blockIdx.x * 256 + threadIdx.x;  // B*S*KVH*16 = 524288
  int c = idx & 15;
  int kvh = (idx >> 4) & 7;
  int s = (idx >> 7) & 2047;
  int b = idx >> 18;
  int d0 = c * 8;
  const bf16* src = qkv + (size_t)(b * 2048 + s) * F_ + kvh * (QPK_ + 2) * D_ + QPK_ * D_ + d0;
  bf16x8 v = *(const bf16x8*)src;
  const float2* tb = tab + s * 64 + (d0 >> 1);
  bf16x8 o;
#pragma unroll
  for (int p = 0; p < 4; ++p) {
    float x0 = (float)v[2 * p], x1 = (float)v[2 * p + 1];
    float2 cs = tb[p];
    o[2 * p]     = (bf16)(x0 * cs.x - x1 * cs.y);
    o[2 * p + 1] = (bf16)(x0 * cs.y + x1 * cs.x);
  }
  *(bf16x8*)(kout + ((size_t)(b * 8 + kvh) * 2048 + s) * 128 + d0) = o;
}

// ---------- V transpose: qkv -> vt[B][KVH][D][S] (LDS tiled 64s x 32d) ----------
__global__ void vtrans_k(const bf16* __restrict__ qkv, bf16* __restrict__ vt) {
  int bidx = blockIdx.x;  // B*KVH*4*32 = 2048
  int st = bidx & 31;
  int dt = (bidx >> 5) & 3;
  int kvh = (bidx >> 7) & 7;
  int b = bidx >> 10;
  __shared__ bf16 tile[64][40];
  int t = threadIdx.x;
  {
    int sl = t >> 2, d0 = (t & 3) * 8;
    bf16x8 v = *(const bf16x8*)(qkv + (size_t)(b * 2048 + st * 64 + sl) * F_ +
                                kvh * (QPK_ + 2) * D_ + (QPK_ + 1) * D_ + dt * 32 + d0);
#pragma unroll
    for (int i = 0; i < 8; ++i) tile[sl][d0 + i] = v[i];
  }
  __syncthreads();
  {
    int dl = t >> 3, s0 = (t & 7) * 8;
    bf16x8 o;
#pragma unroll
    for (int i = 0; i < 8; ++i) o[i] = tile[s0 + i][dl];
    *(bf16x8*)(vt + ((size_t)(b * 8 + kvh) * 128 + dt * 32 + dl) * 2048 + st * 64 + s0) = o;
  }
}

// ---------- causal GQA flash attention ----------
// 512 blocks x 512 thr (8 waves). Block: (b, h, qp); processes q-supertiles
// qp and 15-qp (128 rows each, wave w owns rows qt*128+w*16..+15) -> uniform
// 34 KV-tiles/block; 512 blocks = 2 exact rounds at 1 block/CU (LDS 116KB).
// K/V tri-buffered, staged t+2 ahead, counted vmcnt(4) at boundaries (T4),
// raw barriers. Fully-masked tiles skipped per-wave. XCD-chunked swizzle.
__global__ __launch_bounds__(512, 2)
void attn_k(const bf16* __restrict__ q, const bf16* __restrict__ k,
            const bf16* __restrict__ vt, bf16* __restrict__ ctx) {
  int bid = blockIdx.x;
  bid = (bid & 7) * 64 + (bid >> 3);   // XCD chunk: each XCD gets 2 (b,kvh) KV sets
  int qp = bid & 7;
  int h = (bid >> 3) & 31;
  int b = bid >> 8;
  int kvh = h >> 2;
  int tid = threadIdx.x, w = tid >> 6, lane = tid & 63;
  int l15 = lane & 15, g = lane >> 4;

  __shared__ bf16 Ks[3][64 * 128];   // [s 0..63][d 0..127], 256B rows, swizzled
  __shared__ bf16 Vs[3][128 * 64];   // V^T: [d 0..127][s 0..63], 128B rows, swizzled
  __shared__ bf16 Plds[8][16 * 80];  // per-wave P staging, padded rows

  bf16* Pw = &Plds[w][0];
  const float C2 = 0.08838834764831845f * 1.4426950408889634f;  // scale * log2(e)
  const float NEG = -3.0e38f;

  const bf16* kb_base = k + (size_t)(b * 8 + kvh) * 2048 * 128;
  const bf16* vt_base = vt + (size_t)(b * 8 + kvh) * 128 * 2048;

  // stage one KV tile (K 16KB + V^T 16KB); linear gload_lds dest, inverse-
  // swizzled global source (rule 21); 4 loads/thread.
  auto stage = [&](int kv0, int buf) {
#pragma unroll
    for (int i = 0; i < 2; ++i) {
      int lt = i * 8192 + tid * 16;         // byte offset in K tile
      int row = lt >> 8;                    // 256B rows
      int ch = (lt >> 4) & 15;
      int srcel = (ch ^ (row & 7)) << 3;
      gload16(kb_base + (size_t)(kv0 + row) * 128 + srcel,
              &Ks[buf][(i * 8192 + w * 1024) >> 1]);
    }
#pragma unroll
    for (int i = 0; i < 2; ++i) {
      int lt = i * 8192 + tid * 16;         // byte offset in V tile
      int row = lt >> 7;                    // 128B rows (d index)
      int ch = (lt >> 4) & 7;
      int srcel = (ch ^ (row & 7)) << 3;
      gload16(vt_base + (size_t)row * 2048 + kv0 + srcel,
              &Vs[buf][(i * 8192 + w * 1024) >> 1]);
    }
  };

  const int kxor = (l15 & 7) << 4;

  for (int pass = 0; pass < 2; ++pass) {
    int qt = pass ? (15 - qp) : qp;
    int qrow0 = qt * 128 + w * 16;

    bf16x8 aq[4];
#pragma unroll
    for (int ks = 0; ks < 4; ++ks)
      aq[ks] = *(const bf16x8*)(q + (((size_t)b * 2048 + qrow0 + l15) * 32 + h) * 128 + ks * 32 + g * 8);

    f32x4 acco[8];
#pragma unroll
    for (int n = 0; n < 8; ++n) acco[n] = (f32x4){0.f, 0.f, 0.f, 0.f};
    float m_r[4] = {NEG, NEG, NEG, NEG};
    float l_r[4] = {0.f, 0.f, 0.f, 0.f};

    const int nk = 2 * qt + 2;   // KV tiles needed for 128 q-rows (causal)
    stage(0, 0);
    stage(64, 1);
    asm volatile("s_waitcnt vmcnt(4)");   // t0 landed; t1 in flight
    __builtin_amdgcn_sched_barrier(0);
    __builtin_amdgcn_s_barrier();

    for (int kt = 0; kt < nk; ++kt) {
      int kv0 = kt * 64;
      int cur = kt % 3;
      if (kt + 2 < nk) stage(kv0 + 128, (kt + 2) % 3);

      if (kv0 <= qrow0 + 15) {   // wave-level skip of fully-masked tiles
        f32x4 s[4];
#pragma unroll
        for (int n = 0; n < 4; ++n) s[n] = (f32x4){0.f, 0.f, 0.f, 0.f};
#pragma unroll
        for (int ks = 0; ks < 4; ++ks) {
          int off = ((ks * 64 + g * 16) ^ kxor) >> 1;
#pragma unroll
          for (int n = 0; n < 4; ++n) {
            bf16x8 kb = *(const bf16x8*)&Ks[cur][(n * 16 + l15) * 128 + off];
            s[n] = __builtin_amdgcn_mfma_f32_16x16x32_bf16(aq[ks], kb, s[n], 0, 0, 0);
          }
        }
        if (kv0 + 63 > qrow0) {  // partial tile: causal mask
#pragma unroll
          for (int n = 0; n < 4; ++n)
#pragma unroll
            for (int r = 0; r < 4; ++r) {
              int qg = qrow0 + g * 4 + r;
              int kg = kv0 + n * 16 + l15;
              if (kg > qg) s[n][r] = NEG;
            }
        }
        float fac[4];
#pragma unroll
        for (int r = 0; r < 4; ++r) {
          float mx = fmaxf(fmaxf(s[0][r], s[1][r]), fmaxf(s[2][r], s[3][r]));
#pragma unroll
          for (int off = 1; off < 16; off <<= 1) mx = fmaxf(mx, __shfl_xor(mx, off));
          float mn = fmaxf(m_r[r], mx);
          fac[r] = exp2f((m_r[r] - mn) * C2);
          m_r[r] = mn;
        }
        float psum[4] = {0.f, 0.f, 0.f, 0.f};
#pragma unroll
        for (int n = 0; n < 4; ++n)
#pragma unroll
          for (int r = 0; r < 4; ++r) {
            float p = exp2f((s[n][r] - m_r[r]) * C2);
            psum[r] += p;
            Pw[(g * 4 + r) * 80 + n * 16 + l15] = (bf16)p;
          }
#pragma unroll
        for (int r = 0; r < 4; ++r) {
          float ps = psum[r];
#pragma unroll
          for (int off = 1; off < 16; off <<= 1) ps += __shfl_xor(ps, off);
          l_r[r] = l_r[r] * fac[r] + ps;
        }
#pragma unroll
        for (int n = 0; n < 8; ++n)
#pragma unroll
          for (int r = 0; r < 4; ++r) acco[n][r] *= fac[r];
        // P writes -> P reads (wave-local): fence both sides, clobber-free
        __builtin_amdgcn_sched_barrier(0);
        asm volatile("s_waitcnt lgkmcnt(0)");
        __builtin_amdgcn_sched_barrier(0);
#pragma unroll
        for (int ks = 0; ks < 2; ++ks) {
          bf16x8 pa = *(const bf16x8*)&Pw[l15 * 80 + ks * 32 + g * 8];
          int off = ((ks * 64 + g * 16) ^ kxor) >> 1;
#pragma unroll
          for (int n = 0; n < 8; ++n) {
            bf16x8 vb = *(const bf16x8*)&Vs[cur][(n * 16 + l15) * 64 + off];
            acco[n] = __builtin_amdgcn_mfma_f32_16x16x32_bf16(pa, vb, acco[n], 0, 0, 0);
          }
        }
      }

      if (kt + 1 < nk) {
        if (kt + 2 < nk) { asm volatile("s_waitcnt vmcnt(4)"); }   // t+1 ready
        else             { asm volatile("s_waitcnt vmcnt(0)"); }
        __builtin_amdgcn_sched_barrier(0);
      }
      __builtin_amdgcn_s_barrier();
    }

    // epilogue: normalize and store ctx[B][S][H][D] as bf16
#pragma unroll
    for (int r = 0; r < 4; ++r) {
      float inv = 1.0f / l_r[r];
      int qg = qrow0 + g * 4 + r;
#pragma unroll
      for (int n = 0; n < 8; ++n)
        ctx[(((size_t)b * 2048 + qg) * 32 + h) * 128 + n * 16 + l15] = (bf16)(acco[n][r] * inv);
    }
  }
}

// ---------- launcher ----------
extern "C" void kernel_launch(void* const* d_in, const int* in_sizes, int n_in,
                              void* d_out, int out_size, void* d_ws, size_t ws_size,
                              hipStream_t stream) {
  const float* x = (const float*)d_in[0];
  const float* wqkv = (const float*)d_in[1];
  const float* wo = (const float*)d_in[2];
  float* out = (float*)d_out;
  char* ws = (char*)d_ws;

  // workspace layout (bytes); total = 185,597,952
  bf16* xbf    = (bf16*)(ws + 0);            // 33,554,432  (reused as ctx later)
  bf16* wqkvbf = (bf16*)(ws + 33554432);     // 50,331,648
  bf16* qkvbf  = (bf16*)(ws + 83886080);     // 50,331,648  (reused as wo_bf later)
  bf16* qbuf   = (bf16*)(ws + 134217728);    // 33,554,432
  bf16* kbuf   = (bf16*)(ws + 167772160);    // 8,388,608
  bf16* vtbuf  = (bf16*)(ws + 176160768);    // 8,388,608
  float2* tab  = (float2*)(ws + 184549376);  // 1,048,576

  // 1. converts + rope table
  f2bf_k<<<8192, 256, 0, stream>>>(x, xbf, M_ * E_ / 8);
  f2bf_k<<<12288, 256, 0, stream>>>(wqkv, wqkvbf, F_ * E_ / 8);
  rope_table_k<<<512, 256, 0, stream>>>(tab);

  // 2. QKV projection: qkv[M][F] = x[M][E] * wqkv[F][E]^T
  gemm256<bf16><<<dim3(M_ / 256, F_ / 256), 512, 0, stream>>>(xbf, wqkvbf, qkvbf, M_, F_, E_);

  // 3. RoPE + layout shuffles
  rope_q_k<<<8192, 256, 0, stream>>>(qkvbf, tab, qbuf);
  rope_k_k<<<2048, 256, 0, stream>>>(qkvbf, tab, kbuf);
  vtrans_k<<<2048, 256, 0, stream>>>(qkvbf, vtbuf);

  // 4. convert wo into the (now dead) qkv region
  bf16* wobf = qkvbf;
  f2bf_k<<<8192, 256, 0, stream>>>(wo, wobf, E_ * E_ / 8);

  // 5. attention -> ctx (reuses xbf region, dead after GEMM1)
  bf16* ctx = xbf;
  attn_k<<<512, 512, 0, stream>>>(qbuf, kbuf, vtbuf, ctx);

  // 6. output projection: out[M][E] = ctx[M][E] * wo[E][E]^T  (fp32 out)
  gemm256<float><<<dim3(M_ / 256, E_ / 256), 512, 0, stream>>>(ctx, wobf, out, M_, E_, E_);
}

// Round 6
// 595.809 us; speedup vs baseline: 1.0220x; 1.0220x over previous
//
#include <hip/hip_runtime.h>
#include <cstdint>

// ---------- types ----------
typedef __bf16 bf16;
typedef __bf16 bf16x8 __attribute__((ext_vector_type(8)));
typedef float  f32x4  __attribute__((ext_vector_type(4)));

#define AS1(p) ((__attribute__((address_space(1))) void*)(p))
#define AS3(p) ((__attribute__((address_space(3))) void*)(p))

__device__ __forceinline__ void gload16(const void* g, void* l) {
  __builtin_amdgcn_global_load_lds(AS1(g), AS3(l), 16, 0, 0);
}

// ---------- problem constants ----------
constexpr int B_ = 2, S_ = 2048, E_ = 4096, H_ = 32, KVH_ = 8, D_ = 128;
constexpr int QPK_ = H_ / KVH_;            // 4
constexpr int F_ = E_ + 2 * KVH_ * D_;     // 6144
constexpr int M_ = B_ * S_;                // 4096 rows of x

// ---------- fp32 -> bf16 convert (8 elems/thread) ----------
__global__ void f2bf_k(const float* __restrict__ in, bf16* __restrict__ out, int n8) {
  int i = blockIdx.x * 256 + threadIdx.x;
  if (i >= n8) return;
  const float4* p = (const float4*)(in + (size_t)i * 8);
  float4 a = p[0], b = p[1];
  bf16x8 o;
  o[0] = (bf16)a.x; o[1] = (bf16)a.y; o[2] = (bf16)a.z; o[3] = (bf16)a.w;
  o[4] = (bf16)b.x; o[5] = (bf16)b.y; o[6] = (bf16)b.z; o[7] = (bf16)b.w;
  *(bf16x8*)(out + (size_t)i * 8) = o;
}

// ---------- RoPE cos/sin table ----------
__global__ void rope_table_k(float2* __restrict__ tab) {
  int i = blockIdx.x * 256 + threadIdx.x;   // S_*64 = 131072
  int s = i >> 6, f = i & 63;
  float inv = powf(10000.0f, -2.0f * (float)f / 128.0f);
  float ang = (float)s * inv;
  tab[i] = make_float2(cosf(ang), sinf(ang));
}

// ============ 128x256 2-phase bf16 GEMM (tail-free grids) ============
// C[M][N] = A[M][K] * B[N][K]^T. 512 thr = 8 waves (2M x 4N); per-wave 64x64
// (acc[4][4]); BK=64. TRI-buffered A (3x16KB) and B (3x32KB) = 144KB LDS:
// staging always targets buf (t+2)%3, read last at tile t-1 -> no mid-tile WAR.
// Per K-tile: P1 {A-frags 8 + B-lo 4 reads; stgA(t+2); bar; lgkm0; 16 MFMA; bar}
//             P2 {B-hi 4 reads; stgB(t+2); bar; lgkm0; 16 MFMA; vmcnt(6); bar}
// Counted vmcnt(6) keeps t+2's 6 loads in flight across the boundary (T4).
template <typename OutT>
__global__ __launch_bounds__(512, 2)
void gemm128(const bf16* __restrict__ A, const bf16* __restrict__ B,
             OutT* __restrict__ C, int M, int N, int K) {
  __shared__ bf16 As[3][128 * 64];
  __shared__ bf16 Bs[3][256 * 64];
  const int tid = threadIdx.x;
  const int wid = tid >> 6, lane = tid & 63;
  const int l15 = lane & 15, g = lane >> 4;
  const int wr = wid >> 2, wc = wid & 3;
  const int bm = blockIdx.x, bn = blockIdx.y;
  const bf16* Ab = A + (size_t)bm * 128 * K;
  const bf16* Bb = B + (size_t)bn * 256 * K;
  const int nT = K >> 6;
  const int swzr = (l15 & 7) << 4;

  f32x4 acc[4][4];
#pragma unroll
  for (int m = 0; m < 4; ++m)
#pragma unroll
    for (int n = 0; n < 4; ++n) acc[m][n] = (f32x4){0.f, 0.f, 0.f, 0.f};

  auto stgA = [&](int t) {   // 128x64 tile, 16KB, 2 loads/thread
    bf16* dst = &As[t % 3][0];
#pragma unroll
    for (int i = 0; i < 2; ++i) {
      int lb = i * 8192 + tid * 16;
      int row = lb >> 7;
      int colb = (lb & 127) ^ ((row & 7) << 4);
      gload16(Ab + (size_t)row * K + t * 64 + (colb >> 1),
              dst + ((i * 8192 + wid * 1024) >> 1));
    }
  };
  auto stgB = [&](int t) {   // 256x64 tile, 32KB, 4 loads/thread
    bf16* dst = &Bs[t % 3][0];
#pragma unroll
    for (int i = 0; i < 4; ++i) {
      int lb = i * 8192 + tid * 16;
      int row = lb >> 7;
      int colb = (lb & 127) ^ ((row & 7) << 4);
      gload16(Bb + (size_t)row * K + t * 64 + (colb >> 1),
              dst + ((i * 8192 + wid * 1024) >> 1));
    }
  };

  // ---- prologue: t0 + t1 staged (12 loads); wait t0 (6), keep t1 in flight
  stgA(0); stgB(0);
  if (nT > 1) { stgA(1); stgB(1); asm volatile("s_waitcnt vmcnt(6)"); }
  else        { asm volatile("s_waitcnt vmcnt(0)"); }
  __builtin_amdgcn_sched_barrier(0);
  __builtin_amdgcn_s_barrier();

  bf16x8 af[4][2], blo[2][2], bhi[2][2];
  for (int t = 0; t < nT; ++t) {
    const int cur = t % 3;
    // ---- P1: A-frags + B-lo reads; stage A(t+2) ----
#pragma unroll
    for (int m = 0; m < 4; ++m) {
      int arow = wr * 64 + m * 16 + l15;
#pragma unroll
      for (int ks = 0; ks < 2; ++ks)
        af[m][ks] = *(const bf16x8*)&As[cur][(arow << 6) + (((ks * 64 + g * 16) ^ swzr) >> 1)];
    }
#pragma unroll
    for (int n = 0; n < 2; ++n) {
      int brow = wc * 64 + n * 16 + l15;
#pragma unroll
      for (int ks = 0; ks < 2; ++ks)
        blo[n][ks] = *(const bf16x8*)&Bs[cur][(brow << 6) + (((ks * 64 + g * 16) ^ swzr) >> 1)];
    }
    if (t + 2 < nT) stgA(t + 2);
    __builtin_amdgcn_s_barrier();
    asm volatile("s_waitcnt lgkmcnt(0)");
    __builtin_amdgcn_sched_barrier(0);
    __builtin_amdgcn_s_setprio(1);
#pragma unroll
    for (int ks = 0; ks < 2; ++ks)
#pragma unroll
      for (int m = 0; m < 4; ++m)
#pragma unroll
        for (int n = 0; n < 2; ++n)
          acc[m][n] = __builtin_amdgcn_mfma_f32_16x16x32_bf16(af[m][ks], blo[n][ks], acc[m][n], 0, 0, 0);
    __builtin_amdgcn_s_setprio(0);
    __builtin_amdgcn_s_barrier();
    // ---- P2: B-hi reads; stage B(t+2); boundary counted vmcnt ----
#pragma unroll
    for (int n = 0; n < 2; ++n) {
      int brow = wc * 64 + 32 + n * 16 + l15;
#pragma unroll
      for (int ks = 0; ks < 2; ++ks)
        bhi[n][ks] = *(const bf16x8*)&Bs[cur][(brow << 6) + (((ks * 64 + g * 16) ^ swzr) >> 1)];
    }
    if (t + 2 < nT) stgB(t + 2);
    __builtin_amdgcn_s_barrier();
    asm volatile("s_waitcnt lgkmcnt(0)");
    __builtin_amdgcn_sched_barrier(0);
    __builtin_amdgcn_s_setprio(1);
#pragma unroll
    for (int ks = 0; ks < 2; ++ks)
#pragma unroll
      for (int m = 0; m < 4; ++m)
#pragma unroll
        for (int n = 0; n < 2; ++n)
          acc[m][2 + n] = __builtin_amdgcn_mfma_f32_16x16x32_bf16(af[m][ks], bhi[n][ks], acc[m][2 + n], 0, 0, 0);
    __builtin_amdgcn_s_setprio(0);
    if (t + 2 < nT)      { asm volatile("s_waitcnt vmcnt(6)"); }
    else if (t + 1 < nT) { asm volatile("s_waitcnt vmcnt(0)"); }
    __builtin_amdgcn_sched_barrier(0);
    __builtin_amdgcn_s_barrier();
  }

  // epilogue: C/D layout col=lane&15, row=(lane>>4)*4+r  [measured m89]
#pragma unroll
  for (int m = 0; m < 4; ++m) {
    int row0 = bm * 128 + wr * 64 + m * 16 + g * 4;
#pragma unroll
    for (int n = 0; n < 4; ++n) {
      int col = bn * 256 + wc * 64 + n * 16 + l15;
      f32x4 v = acc[m][n];
#pragma unroll
      for (int r = 0; r < 4; ++r)
        C[(size_t)(row0 + r) * N + col] = (OutT)v[r];
    }
  }
}

// ============ 256x256 4-phase bf16 GEMM (perfect-round grids) ============
// Verified r4 structure; XCD swizzle REVERTED (r5: FETCH +54%, dur +2% — the
// default dispatch order already pins 2 A-panels per XCD and sweeps B-panels
// in temporal lockstep across XCDs).
template <typename OutT>
__global__ __launch_bounds__(512, 2)
void gemm256(const bf16* __restrict__ A, const bf16* __restrict__ B,
             OutT* __restrict__ C, int M, int N, int K) {
  __shared__ bf16 As[2][16384];   // [256 rows][64 el], 128B rows
  __shared__ bf16 Bs[2][16384];
  const int tid = threadIdx.x;
  const int wid = tid >> 6, lane = tid & 63;
  const int l15 = lane & 15, g = lane >> 4;
  const int wr = wid >> 2, wc = wid & 3;
  const int bm = blockIdx.x, bn = blockIdx.y;
  const bf16* Ab = A + (size_t)bm * 256 * K;
  const bf16* Bb = B + (size_t)bn * 256 * K;
  const int nT = K >> 6;
  const int swzr = (l15 & 7) << 4;

  f32x4 acc[8][4];
#pragma unroll
  for (int m = 0; m < 8; ++m)
#pragma unroll
    for (int n = 0; n < 4; ++n) acc[m][n] = (f32x4){0.f, 0.f, 0.f, 0.f};

  auto stg = [&](const bf16* src, bf16* dst, int t, int h) {
#pragma unroll
    for (int i = 0; i < 2; ++i) {
      int lb = h * 16384 + i * 8192 + wid * 1024 + lane * 16;
      int row = lb >> 7;
      int colb = (lb & 127) ^ ((row & 7) << 4);
      gload16(src + (size_t)row * K + t * 64 + (colb >> 1),
              dst + ((h * 16384 + i * 8192 + wid * 1024) >> 1));
    }
  };

  bf16x8 af[4][2];
  bf16x8 bfr[2][2][2];

  stg(Bb, Bs[0], 0, 0); stg(Bb, Bs[0], 0, 1);
  stg(Ab, As[0], 0, 0); stg(Ab, As[0], 0, 1);
  if (nT > 1) {
    stg(Bb, Bs[1], 1, 0); stg(Bb, Bs[1], 1, 1);
    asm volatile("s_waitcnt vmcnt(4)");
  } else {
    asm volatile("s_waitcnt vmcnt(0)");
  }
  __builtin_amdgcn_sched_barrier(0);
  __builtin_amdgcn_s_barrier();

  for (int t = 0; t < nT; ++t) {
    const int cur = t & 1;
    // P1
#pragma unroll
    for (int m = 0; m < 4; ++m) {
      int arow = wr * 128 + m * 16 + l15;
#pragma unroll
      for (int ks = 0; ks < 2; ++ks)
        af[m][ks] = *(const bf16x8*)&As[cur][(arow << 6) + (((ks * 64 + g * 16) ^ swzr) >> 1)];
    }
#pragma unroll
    for (int n = 0; n < 2; ++n) {
      int brow = wc * 64 + n * 16 + l15;
#pragma unroll
      for (int ks = 0; ks < 2; ++ks)
        bfr[0][n][ks] = *(const bf16x8*)&Bs[cur][(brow << 6) + (((ks * 64 + g * 16) ^ swzr) >> 1)];
    }
    if (t + 1 < nT) stg(Ab, As[cur ^ 1], t + 1, 0);
    __builtin_amdgcn_s_barrier();
    asm volatile("s_waitcnt lgkmcnt(0)");
    __builtin_amdgcn_s_setprio(1);
#pragma unroll
    for (int ks = 0; ks < 2; ++ks)
#pragma unroll
      for (int m = 0; m < 4; ++m)
#pragma unroll
        for (int n = 0; n < 2; ++n)
          acc[m][n] = __builtin_amdgcn_mfma_f32_16x16x32_bf16(af[m][ks], bfr[0][n][ks], acc[m][n], 0, 0, 0);
    __builtin_amdgcn_s_setprio(0);
    __builtin_amdgcn_s_barrier();
    // P2
#pragma unroll
    for (int n = 0; n < 2; ++n) {
      int brow = wc * 64 + 32 + n * 16 + l15;
#pragma unroll
      for (int ks = 0; ks < 2; ++ks)
        bfr[1][n][ks] = *(const bf16x8*)&Bs[cur][(brow << 6) + (((ks * 64 + g * 16) ^ swzr) >> 1)];
    }
    if (t + 1 < nT) stg(Ab, As[cur ^ 1], t + 1, 1);
    __builtin_amdgcn_s_barrier();
    asm volatile("s_waitcnt lgkmcnt(0)");
    __builtin_amdgcn_s_setprio(1);
#pragma unroll
    for (int ks = 0; ks < 2; ++ks)
#pragma unroll
      for (int m = 0; m < 4; ++m)
#pragma unroll
        for (int n = 0; n < 2; ++n)
          acc[m][2 + n] = __builtin_amdgcn_mfma_f32_16x16x32_bf16(af[m][ks], bfr[1][n][ks], acc[m][2 + n], 0, 0, 0);
    __builtin_amdgcn_s_setprio(0);
    __builtin_amdgcn_s_barrier();
    // P3
#pragma unroll
    for (int m = 0; m < 4; ++m) {
      int arow = wr * 128 + 64 + m * 16 + l15;
#pragma unroll
      for (int ks = 0; ks < 2; ++ks)
        af[m][ks] = *(const bf16x8*)&As[cur][(arow << 6) + (((ks * 64 + g * 16) ^ swzr) >> 1)];
    }
    if (t + 2 < nT) stg(Bb, Bs[cur], t + 2, 0);
    __builtin_amdgcn_s_barrier();
    asm volatile("s_waitcnt lgkmcnt(0)");
    __builtin_amdgcn_s_setprio(1);
#pragma unroll
    for (int ks = 0; ks < 2; ++ks)
#pragma unroll
      for (int m = 0; m < 4; ++m)
#pragma unroll
        for (int n = 0; n < 2; ++n)
          acc[4 + m][n] = __builtin_amdgcn_mfma_f32_16x16x32_bf16(af[m][ks], bfr[0][n][ks], acc[4 + m][n], 0, 0, 0);
    __builtin_amdgcn_s_setprio(0);
    __builtin_amdgcn_s_barrier();
    // P4
    if (t + 2 < nT) stg(Bb, Bs[cur], t + 2, 1);
    __builtin_amdgcn_s_setprio(1);
#pragma unroll
    for (int ks = 0; ks < 2; ++ks)
#pragma unroll
      for (int m = 0; m < 4; ++m)
#pragma unroll
        for (int n = 0; n < 2; ++n)
          acc[4 + m][2 + n] = __builtin_amdgcn_mfma_f32_16x16x32_bf16(af[m][ks], bfr[1][n][ks], acc[4 + m][2 + n], 0, 0, 0);
    __builtin_amdgcn_s_setprio(0);
    if (t + 2 < nT)      { asm volatile("s_waitcnt vmcnt(4)"); }
    else if (t + 1 < nT) { asm volatile("s_waitcnt vmcnt(0)"); }
    __builtin_amdgcn_sched_barrier(0);
    __builtin_amdgcn_s_barrier();
  }

#pragma unroll
  for (int mh = 0; mh < 2; ++mh)
#pragma unroll
    for (int m = 0; m < 4; ++m) {
      int row0 = bm * 256 + wr * 128 + mh * 64 + m * 16 + g * 4;
#pragma unroll
      for (int nh = 0; nh < 2; ++nh)
#pragma unroll
        for (int n = 0; n < 2; ++n) {
          int col = bn * 256 + wc * 64 + nh * 32 + n * 16 + l15;
          f32x4 v = acc[mh * 4 + m][nh * 2 + n];
#pragma unroll
          for (int r = 0; r < 4; ++r)
            C[(size_t)(row0 + r) * N + col] = (OutT)v[r];
        }
    }
}

// ---------- RoPE on Q: qkv[M][F] -> q[B][S][H][D] (interleaved pairs) ----------
__global__ void rope_q_k(const bf16* __restrict__ qkv, const float2* __restrict__ tab,
                         bf16* __restrict__ qout) {
  int idx = blockIdx.x * 256 + threadIdx.x;  // B*S*H*16 = 2097152
  int c = idx & 15;
  int h = (idx >> 4) & 31;
  int s = (idx >> 9) & 2047;
  int b = idx >> 20;
  int d0 = c * 8;
  int kvh = h >> 2, j = h & 3;
  const bf16* src = qkv + (size_t)(b * 2048 + s) * F_ + kvh * (QPK_ + 2) * D_ + j * D_ + d0;
  bf16x8 v = *(const bf16x8*)src;
  const float2* tb = tab + s * 64 + (d0 >> 1);
  bf16x8 o;
#pragma unroll
  for (int p = 0; p < 4; ++p) {
    float x0 = (float)v[2 * p], x1 = (float)v[2 * p + 1];
    float2 cs = tb[p];
    o[2 * p]     = (bf16)(x0 * cs.x - x1 * cs.y);
    o[2 * p + 1] = (bf16)(x0 * cs.y + x1 * cs.x);
  }
  *(bf16x8*)(qout + (((size_t)b * 2048 + s) * 32 + h) * 128 + d0) = o;
}

// ---------- RoPE on K: qkv -> k[B][KVH][S][D] ----------
__global__ void rope_k_k(const bf16* __restrict__ qkv, const float2* __restrict__ tab,
                         bf16* __restrict__ kout) {
  int idx = blockIdx.x * 256 + threadIdx.x;  // B*S*KVH*16 = 524288
  int c = idx & 15;
  int kvh = (idx >> 4) & 7;
  int s = (idx >> 7) & 2047;
  int b = idx >> 18;
  int d0 = c * 8;
  const bf16* src = qkv + (size_t)(b * 2048 + s) * F_ + kvh * (QPK_ + 2) * D_ + QPK_ * D_ + d0;
  bf16x8 v = *(const bf16x8*)src;
  const float2* tb = tab + s * 64 + (d0 >> 1);
  bf16x8 o;
#pragma unroll
  for (int p = 0; p < 4; ++p) {
    float x0 = (float)v[2 * p], x1 = (float)v[2 * p + 1];
    float2 cs = tb[p];
    o[2 * p]     = (bf16)(x0 * cs.x - x1 * cs.y);
    o[2 * p + 1] = (bf16)(x0 * cs.y + x1 * cs.x);
  }
  *(bf16x8*)(kout + ((size_t)(b * 8 + kvh) * 2048 + s) * 128 + d0) = o;
}

// ---------- V transpose: qkv -> vt[B][KVH][D][S] (LDS tiled 64s x 32d) ----------
__global__ void vtrans_k(const bf16* __restrict__ qkv, bf16* __restrict__ vt) {
  int bidx = blockIdx.x;  // B*KVH*4*32 = 2048
  int st = bidx & 31;
  int dt = (bidx >> 5) & 3;
  int kvh = (bidx >> 7) & 7;
  int b = bidx >> 10;
  __shared__ bf16 tile[64][40];
  int t = threadIdx.x;
  {
    int sl = t >> 2, d0 = (t & 3) * 8;
    bf16x8 v = *(const bf16x8*)(qkv + (size_t)(b * 2048 + st * 64 + sl) * F_ +
                                kvh * (QPK_ + 2) * D_ + (QPK_ + 1) * D_ + dt * 32 + d0);
#pragma unroll
    for (int i = 0; i < 8; ++i) tile[sl][d0 + i] = v[i];
  }
  __syncthreads();
  {
    int dl = t >> 3, s0 = (t & 7) * 8;
    bf16x8 o;
#pragma unroll
    for (int i = 0; i < 8; ++i) o[i] = tile[s0 + i][dl];
    *(bf16x8*)(vt + ((size_t)(b * 8 + kvh) * 128 + dt * 32 + dl) * 2048 + st * 64 + s0) = o;
  }
}

// ---------- causal GQA flash attention (r5 structure, unchanged) ----------
__global__ __launch_bounds__(512, 2)
void attn_k(const bf16* __restrict__ q, const bf16* __restrict__ k,
            const bf16* __restrict__ vt, bf16* __restrict__ ctx) {
  int bid = blockIdx.x;
  bid = (bid & 7) * 64 + (bid >> 3);   // XCD chunk: each XCD gets 2 (b,kvh) KV sets
  int qp = bid & 7;
  int h = (bid >> 3) & 31;
  int b = bid >> 8;
  int kvh = h >> 2;
  int tid = threadIdx.x, w = tid >> 6, lane = tid & 63;
  int l15 = lane & 15, g = lane >> 4;

  __shared__ bf16 Ks[3][64 * 128];
  __shared__ bf16 Vs[3][128 * 64];
  __shared__ bf16 Plds[8][16 * 80];

  bf16* Pw = &Plds[w][0];
  const float C2 = 0.08838834764831845f * 1.4426950408889634f;
  const float NEG = -3.0e38f;

  const bf16* kb_base = k + (size_t)(b * 8 + kvh) * 2048 * 128;
  const bf16* vt_base = vt + (size_t)(b * 8 + kvh) * 128 * 2048;

  auto stage = [&](int kv0, int buf) {
#pragma unroll
    for (int i = 0; i < 2; ++i) {
      int lt = i * 8192 + tid * 16;
      int row = lt >> 8;
      int ch = (lt >> 4) & 15;
      int srcel = (ch ^ (row & 7)) << 3;
      gload16(kb_base + (size_t)(kv0 + row) * 128 + srcel,
              &Ks[buf][(i * 8192 + w * 1024) >> 1]);
    }
#pragma unroll
    for (int i = 0; i < 2; ++i) {
      int lt = i * 8192 + tid * 16;
      int row = lt >> 7;
      int ch = (lt >> 4) & 7;
      int srcel = (ch ^ (row & 7)) << 3;
      gload16(vt_base + (size_t)row * 2048 + kv0 + srcel,
              &Vs[buf][(i * 8192 + w * 1024) >> 1]);
    }
  };

  const int kxor = (l15 & 7) << 4;

  for (int pass = 0; pass < 2; ++pass) {
    int qt = pass ? (15 - qp) : qp;
    int qrow0 = qt * 128 + w * 16;

    bf16x8 aq[4];
#pragma unroll
    for (int ks = 0; ks < 4; ++ks)
      aq[ks] = *(const bf16x8*)(q + (((size_t)b * 2048 + qrow0 + l15) * 32 + h) * 128 + ks * 32 + g * 8);

    f32x4 acco[8];
#pragma unroll
    for (int n = 0; n < 8; ++n) acco[n] = (f32x4){0.f, 0.f, 0.f, 0.f};
    float m_r[4] = {NEG, NEG, NEG, NEG};
    float l_r[4] = {0.f, 0.f, 0.f, 0.f};

    const int nk = 2 * qt + 2;
    stage(0, 0);
    stage(64, 1);
    asm volatile("s_waitcnt vmcnt(4)");
    __builtin_amdgcn_sched_barrier(0);
    __builtin_amdgcn_s_barrier();

    for (int kt = 0; kt < nk; ++kt) {
      int kv0 = kt * 64;
      int cur = kt % 3;
      if (kt + 2 < nk) stage(kv0 + 128, (kt + 2) % 3);

      if (kv0 <= qrow0 + 15) {
        f32x4 s[4];
#pragma unroll
        for (int n = 0; n < 4; ++n) s[n] = (f32x4){0.f, 0.f, 0.f, 0.f};
#pragma unroll
        for (int ks = 0; ks < 4; ++ks) {
          int off = ((ks * 64 + g * 16) ^ kxor) >> 1;
#pragma unroll
          for (int n = 0; n < 4; ++n) {
            bf16x8 kb = *(const bf16x8*)&Ks[cur][(n * 16 + l15) * 128 + off];
            s[n] = __builtin_amdgcn_mfma_f32_16x16x32_bf16(aq[ks], kb, s[n], 0, 0, 0);
          }
        }
        if (kv0 + 63 > qrow0) {
#pragma unroll
          for (int n = 0; n < 4; ++n)
#pragma unroll
            for (int r = 0; r < 4; ++r) {
              int qg = qrow0 + g * 4 + r;
              int kg = kv0 + n * 16 + l15;
              if (kg > qg) s[n][r] = NEG;
            }
        }
        float fac[4];
#pragma unroll
        for (int r = 0; r < 4; ++r) {
          float mx = fmaxf(fmaxf(s[0][r], s[1][r]), fmaxf(s[2][r], s[3][r]));
#pragma unroll
          for (int off = 1; off < 16; off <<= 1) mx = fmaxf(mx, __shfl_xor(mx, off));
          float mn = fmaxf(m_r[r], mx);
          fac[r] = exp2f((m_r[r] - mn) * C2);
          m_r[r] = mn;
        }
        float psum[4] = {0.f, 0.f, 0.f, 0.f};
#pragma unroll
        for (int n = 0; n < 4; ++n)
#pragma unroll
          for (int r = 0; r < 4; ++r) {
            float p = exp2f((s[n][r] - m_r[r]) * C2);
            psum[r] += p;
            Pw[(g * 4 + r) * 80 + n * 16 + l15] = (bf16)p;
          }
#pragma unroll
        for (int r = 0; r < 4; ++r) {
          float ps = psum[r];
#pragma unroll
          for (int off = 1; off < 16; off <<= 1) ps += __shfl_xor(ps, off);
          l_r[r] = l_r[r] * fac[r] + ps;
        }
#pragma unroll
        for (int n = 0; n < 8; ++n)
#pragma unroll
          for (int r = 0; r < 4; ++r) acco[n][r] *= fac[r];
        __builtin_amdgcn_sched_barrier(0);
        asm volatile("s_waitcnt lgkmcnt(0)");
        __builtin_amdgcn_sched_barrier(0);
#pragma unroll
        for (int ks = 0; ks < 2; ++ks) {
          bf16x8 pa = *(const bf16x8*)&Pw[l15 * 80 + ks * 32 + g * 8];
          int off = ((ks * 64 + g * 16) ^ kxor) >> 1;
#pragma unroll
          for (int n = 0; n < 8; ++n) {
            bf16x8 vb = *(const bf16x8*)&Vs[cur][(n * 16 + l15) * 64 + off];
            acco[n] = __builtin_amdgcn_mfma_f32_16x16x32_bf16(pa, vb, acco[n], 0, 0, 0);
          }
        }
      }

      if (kt + 1 < nk) {
        if (kt + 2 < nk) { asm volatile("s_waitcnt vmcnt(4)"); }
        else             { asm volatile("s_waitcnt vmcnt(0)"); }
        __builtin_amdgcn_sched_barrier(0);
      }
      __builtin_amdgcn_s_barrier();
    }

#pragma unroll
    for (int r = 0; r < 4; ++r) {
      float inv = 1.0f / l_r[r];
      int qg = qrow0 + g * 4 + r;
#pragma unroll
      for (int n = 0; n < 8; ++n)
        ctx[(((size_t)b * 2048 + qg) * 32 + h) * 128 + n * 16 + l15] = (bf16)(acco[n][r] * inv);
    }
  }
}

// ---------- launcher ----------
extern "C" void kernel_launch(void* const* d_in, const int* in_sizes, int n_in,
                              void* d_out, int out_size, void* d_ws, size_t ws_size,
                              hipStream_t stream) {
  const float* x = (const float*)d_in[0];
  const float* wqkv = (const float*)d_in[1];
  const float* wo = (const float*)d_in[2];
  float* out = (float*)d_out;
  char* ws = (char*)d_ws;

  // workspace layout (bytes); total = 185,597,952
  bf16* xbf    = (bf16*)(ws + 0);            // 33,554,432  (reused as ctx later)
  bf16* wqkvbf = (bf16*)(ws + 33554432);     // 50,331,648
  bf16* qkvbf  = (bf16*)(ws + 83886080);     // 50,331,648  (reused as wo_bf later)
  bf16* qbuf   = (bf16*)(ws + 134217728);    // 33,554,432
  bf16* kbuf   = (bf16*)(ws + 167772160);    // 8,388,608
  bf16* vtbuf  = (bf16*)(ws + 176160768);    // 8,388,608
  float2* tab  = (float2*)(ws + 184549376);  // 1,048,576

  // 1. converts + rope table
  f2bf_k<<<8192, 256, 0, stream>>>(x, xbf, M_ * E_ / 8);
  f2bf_k<<<12288, 256, 0, stream>>>(wqkv, wqkvbf, F_ * E_ / 8);
  rope_table_k<<<512, 256, 0, stream>>>(tab);

  // 2. QKV projection: qkv[M][F] = x[M][E] * wqkv[F][E]^T
  //    128x256 tiles -> 32x24 = 768 blocks = 3 exact rounds (no tail)
  gemm128<bf16><<<dim3(M_ / 128, F_ / 256), 512, 0, stream>>>(xbf, wqkvbf, qkvbf, M_, F_, E_);

  // 3. RoPE + layout shuffles
  rope_q_k<<<8192, 256, 0, stream>>>(qkvbf, tab, qbuf);
  rope_k_k<<<2048, 256, 0, stream>>>(qkvbf, tab, kbuf);
  vtrans_k<<<2048, 256, 0, stream>>>(qkvbf, vtbuf);

  // 4. convert wo into the (now dead) qkv region
  bf16* wobf = qkvbf;
  f2bf_k<<<8192, 256, 0, stream>>>(wo, wobf, E_ * E_ / 8);

  // 5. attention -> ctx (reuses xbf region, dead after GEMM1)
  bf16* ctx = xbf;
  attn_k<<<512, 512, 0, stream>>>(qbuf, kbuf, vtbuf, ctx);

  // 6. output projection: 256x256 tiles -> 16x16 = 256 blocks = 1 exact round
  gemm256<float><<<dim3(M_ / 256, E_ / 256), 512, 0, stream>>>(ctx, wobf, out, M_, E_, E_);
}

// Round 7
// 590.016 us; speedup vs baseline: 1.0320x; 1.0098x over previous
//
#include <hip/hip_runtime.h>
#include <cstdint>

// ---------- types ----------
typedef __bf16 bf16;
typedef __bf16 bf16x8 __attribute__((ext_vector_type(8)));
typedef float  f32x4  __attribute__((ext_vector_type(4)));

#define AS1(p) ((__attribute__((address_space(1))) void*)(p))
#define AS3(p) ((__attribute__((address_space(3))) void*)(p))

__device__ __forceinline__ void gload16(const void* g, void* l) {
  __builtin_amdgcn_global_load_lds(AS1(g), AS3(l), 16, 0, 0);
}

// ---------- problem constants ----------
constexpr int B_ = 2, S_ = 2048, E_ = 4096, H_ = 32, KVH_ = 8, D_ = 128;
constexpr int QPK_ = H_ / KVH_;            // 4
constexpr int F_ = E_ + 2 * KVH_ * D_;     // 6144
constexpr int M_ = B_ * S_;                // 4096 rows of x

// ---------- fp32 -> bf16 convert (8 elems/thread) ----------
__global__ void f2bf_k(const float* __restrict__ in, bf16* __restrict__ out, int n8) {
  int i = blockIdx.x * 256 + threadIdx.x;
  if (i >= n8) return;
  const float4* p = (const float4*)(in + (size_t)i * 8);
  float4 a = p[0], b = p[1];
  bf16x8 o;
  o[0] = (bf16)a.x; o[1] = (bf16)a.y; o[2] = (bf16)a.z; o[3] = (bf16)a.w;
  o[4] = (bf16)b.x; o[5] = (bf16)b.y; o[6] = (bf16)b.z; o[7] = (bf16)b.w;
  *(bf16x8*)(out + (size_t)i * 8) = o;
}

// ---------- RoPE cos/sin table ----------
__global__ void rope_table_k(float2* __restrict__ tab) {
  int i = blockIdx.x * 256 + threadIdx.x;   // S_*64 = 131072
  int s = i >> 6, f = i & 63;
  float inv = powf(10000.0f, -2.0f * (float)f / 128.0f);
  float ang = (float)s * inv;
  tab[i] = make_float2(cosf(ang), sinf(ang));
}

// ============ 256x256 4-phase bf16 GEMM, PAIR-UNROLLED K-loop ============
// C[M][N] = A[M][K]*B[N][K]^T. 512 thr = 8 waves (2M x 4N); per-wave 128x64
// (acc[8][4]); BK=64; LDS 128KB dbuf. K-loop iterates PAIRS of K-tiles with
// `cur` as an inlined LITERAL (m201's "8 phases/iter, 2 K-tiles/iter"):
// runtime-cur (r4-r6) kept every ds_read/stage address in VALU (VALUBusy 15-21%)
// and blocked base+imm folding -> MfmaUtil stuck at 36%. Swizzle via pre-swz
// global source (rule 21); counted vmcnt(4)/K-tile; raw barriers; clobber-free
// waits; setprio around MFMA.
template <typename OutT>
__global__ __launch_bounds__(512, 2)
void gemm256(const bf16* __restrict__ A, const bf16* __restrict__ B,
             OutT* __restrict__ C, int M, int N, int K) {
  __shared__ bf16 As[2][16384];   // [256 rows][64 el], 128B rows
  __shared__ bf16 Bs[2][16384];
  const int tid = threadIdx.x;
  const int wid = tid >> 6, lane = tid & 63;
  const int l15 = lane & 15, g = lane >> 4;
  const int wr = wid >> 2, wc = wid & 3;
  const int bm = blockIdx.x, bn = blockIdx.y;
  const bf16* Ab = A + (size_t)bm * 256 * K;
  const bf16* Bb = B + (size_t)bn * 256 * K;
  const int nT = K >> 6;            // must be even (K multiple of 128)
  const int swzr = (l15 & 7) << 4;  // read-side byte swizzle for row = *+l15

  f32x4 acc[8][4];
#pragma unroll
  for (int m = 0; m < 8; ++m)
#pragma unroll
    for (int n = 0; n < 4; ++n) acc[m][n] = (f32x4){0.f, 0.f, 0.f, 0.f};

  // stage half-tile h (rows h*128..+127) of K-tile t; linear gload_lds dest,
  // inverse-swizzled global source column.
  auto stg = [&](const bf16* src, bf16* dst, int t, int h) {
#pragma unroll
    for (int i = 0; i < 2; ++i) {
      int lb = h * 16384 + i * 8192 + wid * 1024 + lane * 16;
      int row = lb >> 7;
      int colb = (lb & 127) ^ ((row & 7) << 4);
      gload16(src + (size_t)row * K + t * 64 + (colb >> 1),
              dst + ((h * 16384 + i * 8192 + wid * 1024) >> 1));
    }
  };

  bf16x8 af[4][2];
  bf16x8 bfr[2][2][2];

  // ---- prologue: t0 full + t1 B-halves; wait t0 landed (keep t1B in flight)
  stg(Bb, Bs[0], 0, 0); stg(Bb, Bs[0], 0, 1);
  stg(Ab, As[0], 0, 0); stg(Ab, As[0], 0, 1);
  if (nT > 1) {
    stg(Bb, Bs[1], 1, 0); stg(Bb, Bs[1], 1, 1);
    asm volatile("s_waitcnt vmcnt(4)");
  } else {
    asm volatile("s_waitcnt vmcnt(0)");
  }
  __builtin_amdgcn_sched_barrier(0);
  __builtin_amdgcn_s_barrier();

  // one K-tile; cur MUST be a literal at the call site (inlined -> folded).
  auto tileK = [&](int t, const int cur) {
    // -------- P1: A-lo + B-lo reads; stage (t+1) A0 --------
#pragma unroll
    for (int m = 0; m < 4; ++m) {
      int arow = wr * 128 + m * 16 + l15;
#pragma unroll
      for (int ks = 0; ks < 2; ++ks)
        af[m][ks] = *(const bf16x8*)&As[cur][(arow << 6) + (((ks * 64 + g * 16) ^ swzr) >> 1)];
    }
#pragma unroll
    for (int n = 0; n < 2; ++n) {
      int brow = wc * 64 + n * 16 + l15;
#pragma unroll
      for (int ks = 0; ks < 2; ++ks)
        bfr[0][n][ks] = *(const bf16x8*)&Bs[cur][(brow << 6) + (((ks * 64 + g * 16) ^ swzr) >> 1)];
    }
    if (t + 1 < nT) stg(Ab, As[cur ^ 1], t + 1, 0);
    __builtin_amdgcn_s_barrier();
    asm volatile("s_waitcnt lgkmcnt(0)");
    __builtin_amdgcn_s_setprio(1);
#pragma unroll
    for (int ks = 0; ks < 2; ++ks)
#pragma unroll
      for (int m = 0; m < 4; ++m)
#pragma unroll
        for (int n = 0; n < 2; ++n)
          acc[m][n] = __builtin_amdgcn_mfma_f32_16x16x32_bf16(af[m][ks], bfr[0][n][ks], acc[m][n], 0, 0, 0);
    __builtin_amdgcn_s_setprio(0);
    __builtin_amdgcn_s_barrier();
    // -------- P2: B-hi reads; stage (t+1) A1 --------
#pragma unroll
    for (int n = 0; n < 2; ++n) {
      int brow = wc * 64 + 32 + n * 16 + l15;
#pragma unroll
      for (int ks = 0; ks < 2; ++ks)
        bfr[1][n][ks] = *(const bf16x8*)&Bs[cur][(brow << 6) + (((ks * 64 + g * 16) ^ swzr) >> 1)];
    }
    if (t + 1 < nT) stg(Ab, As[cur ^ 1], t + 1, 1);
    __builtin_amdgcn_s_barrier();
    asm volatile("s_waitcnt lgkmcnt(0)");
    __builtin_amdgcn_s_setprio(1);
#pragma unroll
    for (int ks = 0; ks < 2; ++ks)
#pragma unroll
      for (int m = 0; m < 4; ++m)
#pragma unroll
        for (int n = 0; n < 2; ++n)
          acc[m][2 + n] = __builtin_amdgcn_mfma_f32_16x16x32_bf16(af[m][ks], bfr[1][n][ks], acc[m][2 + n], 0, 0, 0);
    __builtin_amdgcn_s_setprio(0);
    __builtin_amdgcn_s_barrier();
    // -------- P3: A-hi reads; stage (t+2) B0 --------
#pragma unroll
    for (int m = 0; m < 4; ++m) {
      int arow = wr * 128 + 64 + m * 16 + l15;
#pragma unroll
      for (int ks = 0; ks < 2; ++ks)
        af[m][ks] = *(const bf16x8*)&As[cur][(arow << 6) + (((ks * 64 + g * 16) ^ swzr) >> 1)];
    }
    if (t + 2 < nT) stg(Bb, Bs[cur], t + 2, 0);
    __builtin_amdgcn_s_barrier();
    asm volatile("s_waitcnt lgkmcnt(0)");
    __builtin_amdgcn_s_setprio(1);
#pragma unroll
    for (int ks = 0; ks < 2; ++ks)
#pragma unroll
      for (int m = 0; m < 4; ++m)
#pragma unroll
        for (int n = 0; n < 2; ++n)
          acc[4 + m][n] = __builtin_amdgcn_mfma_f32_16x16x32_bf16(af[m][ks], bfr[0][n][ks], acc[4 + m][n], 0, 0, 0);
    __builtin_amdgcn_s_setprio(0);
    __builtin_amdgcn_s_barrier();
    // -------- P4: stage (t+2) B1; MFMA; counted boundary vmcnt --------
    if (t + 2 < nT) stg(Bb, Bs[cur], t + 2, 1);
    __builtin_amdgcn_s_setprio(1);
#pragma unroll
    for (int ks = 0; ks < 2; ++ks)
#pragma unroll
      for (int m = 0; m < 4; ++m)
#pragma unroll
        for (int n = 0; n < 2; ++n)
          acc[4 + m][2 + n] = __builtin_amdgcn_mfma_f32_16x16x32_bf16(af[m][ks], bfr[1][n][ks], acc[4 + m][2 + n], 0, 0, 0);
    __builtin_amdgcn_s_setprio(0);
    if (t + 2 < nT)      { asm volatile("s_waitcnt vmcnt(4)"); }
    else if (t + 1 < nT) { asm volatile("s_waitcnt vmcnt(0)"); }
    __builtin_amdgcn_sched_barrier(0);   // pin next-tile ds_reads below the wait
    __builtin_amdgcn_s_barrier();
  };

  // pair-unrolled main loop: cur is a literal in each inlined copy
  for (int tt = 0; tt < nT; tt += 2) {
    tileK(tt, 0);
    tileK(tt + 1, 1);
  }

  // epilogue: C/D layout col=lane&15, row=(lane>>4)*4+r  [measured m89]
#pragma unroll
  for (int mh = 0; mh < 2; ++mh)
#pragma unroll
    for (int m = 0; m < 4; ++m) {
      int row0 = bm * 256 + wr * 128 + mh * 64 + m * 16 + g * 4;
#pragma unroll
      for (int nh = 0; nh < 2; ++nh)
#pragma unroll
        for (int n = 0; n < 2; ++n) {
          int col = bn * 256 + wc * 64 + nh * 32 + n * 16 + l15;
          f32x4 v = acc[mh * 4 + m][nh * 2 + n];
#pragma unroll
          for (int r = 0; r < 4; ++r)
            C[(size_t)(row0 + r) * N + col] = (OutT)v[r];
        }
    }
}

// ---------- RoPE on Q: qkv[M][F] -> q[B][S][H][D] (interleaved pairs) ----------
__global__ void rope_q_k(const bf16* __restrict__ qkv, const float2* __restrict__ tab,
                         bf16* __restrict__ qout) {
  int idx = blockIdx.x * 256 + threadIdx.x;  // B*S*H*16 = 2097152
  int c = idx & 15;
  int h = (idx >> 4) & 31;
  int s = (idx >> 9) & 2047;
  int b = idx >> 20;
  int d0 = c * 8;
  int kvh = h >> 2, j = h & 3;
  const bf16* src = qkv + (size_t)(b * 2048 + s) * F_ + kvh * (QPK_ + 2) * D_ + j * D_ + d0;
  bf16x8 v = *(const bf16x8*)src;
  const float2* tb = tab + s * 64 + (d0 >> 1);
  bf16x8 o;
#pragma unroll
  for (int p = 0; p < 4; ++p) {
    float x0 = (float)v[2 * p], x1 = (float)v[2 * p + 1];
    float2 cs = tb[p];
    o[2 * p]     = (bf16)(x0 * cs.x - x1 * cs.y);
    o[2 * p + 1] = (bf16)(x0 * cs.y + x1 * cs.x);
  }
  *(bf16x8*)(qout + (((size_t)b * 2048 + s) * 32 + h) * 128 + d0) = o;
}

// ---------- RoPE on K: qkv -> k[B][KVH][S][D] ----------
__global__ void rope_k_k(const bf16* __restrict__ qkv, const float2* __restrict__ tab,
                         bf16* __restrict__ kout) {
  int idx = blockIdx.x * 256 + threadIdx.x;  // B*S*KVH*16 = 524288
  int c = idx & 15;
  int kvh = (idx >> 4) & 7;
  int s = (idx >> 7) & 2047;
  int b = idx >> 18;
  int d0 = c * 8;
  const bf16* src = qkv + (size_t)(b * 2048 + s) * F_ + kvh * (QPK_ + 2) * D_ + QPK_ * D_ + d0;
  bf16x8 v = *(const bf16x8*)src;
  const float2* tb = tab + s * 64 + (d0 >> 1);
  bf16x8 o;
#pragma unroll
  for (int p = 0; p < 4; ++p) {
    float x0 = (float)v[2 * p], x1 = (float)v[2 * p + 1];
    float2 cs = tb[p];
    o[2 * p]     = (bf16)(x0 * cs.x - x1 * cs.y);
    o[2 * p + 1] = (bf16)(x0 * cs.y + x1 * cs.x);
  }
  *(bf16x8*)(kout + ((size_t)(b * 8 + kvh) * 2048 + s) * 128 + d0) = o;
}

// ---------- V transpose: qkv -> vt[B][KVH][D][S] (LDS tiled 64s x 32d) ----------
__global__ void vtrans_k(const bf16* __restrict__ qkv, bf16* __restrict__ vt) {
  int bidx = blockIdx.x;  // B*KVH*4*32 = 2048
  int st = bidx & 31;
  int dt = (bidx >> 5) & 3;
  int kvh = (bidx >> 7) & 7;
  int b = bidx >> 10;
  __shared__ bf16 tile[64][40];
  int t = threadIdx.x;
  {
    int sl = t >> 2, d0 = (t & 3) * 8;
    bf16x8 v = *(const bf16x8*)(qkv + (size_t)(b * 2048 + st * 64 + sl) * F_ +
                                kvh * (QPK_ + 2) * D_ + (QPK_ + 1) * D_ + dt * 32 + d0);
#pragma unroll
    for (int i = 0; i < 8; ++i) tile[sl][d0 + i] = v[i];
  }
  __syncthreads();
  {
    int dl = t >> 3, s0 = (t & 7) * 8;
    bf16x8 o;
#pragma unroll
    for (int i = 0; i < 8; ++i) o[i] = tile[s0 + i][dl];
    *(bf16x8*)(vt + ((size_t)(b * 8 + kvh) * 128 + dt * 32 + dl) * 2048 + st * 64 + s0) = o;
  }
}

// ---------- causal GQA flash attention (r5 structure, unchanged) ----------
__global__ __launch_bounds__(512, 2)
void attn_k(const bf16* __restrict__ q, const bf16* __restrict__ k,
            const bf16* __restrict__ vt, bf16* __restrict__ ctx) {
  int bid = blockIdx.x;
  bid = (bid & 7) * 64 + (bid >> 3);   // XCD chunk: each XCD gets 2 (b,kvh) KV sets
  int qp = bid & 7;
  int h = (bid >> 3) & 31;
  int b = bid >> 8;
  int kvh = h >> 2;
  int tid = threadIdx.x, w = tid >> 6, lane = tid & 63;
  int l15 = lane & 15, g = lane >> 4;

  __shared__ bf16 Ks[3][64 * 128];
  __shared__ bf16 Vs[3][128 * 64];
  __shared__ bf16 Plds[8][16 * 80];

  bf16* Pw = &Plds[w][0];
  const float C2 = 0.08838834764831845f * 1.4426950408889634f;
  const float NEG = -3.0e38f;

  const bf16* kb_base = k + (size_t)(b * 8 + kvh) * 2048 * 128;
  const bf16* vt_base = vt + (size_t)(b * 8 + kvh) * 128 * 2048;

  auto stage = [&](int kv0, int buf) {
#pragma unroll
    for (int i = 0; i < 2; ++i) {
      int lt = i * 8192 + tid * 16;
      int row = lt >> 8;
      int ch = (lt >> 4) & 15;
      int srcel = (ch ^ (row & 7)) << 3;
      gload16(kb_base + (size_t)(kv0 + row) * 128 + srcel,
              &Ks[buf][(i * 8192 + w * 1024) >> 1]);
    }
#pragma unroll
    for (int i = 0; i < 2; ++i) {
      int lt = i * 8192 + tid * 16;
      int row = lt >> 7;
      int ch = (lt >> 4) & 7;
      int srcel = (ch ^ (row & 7)) << 3;
      gload16(vt_base + (size_t)row * 2048 + kv0 + srcel,
              &Vs[buf][(i * 8192 + w * 1024) >> 1]);
    }
  };

  const int kxor = (l15 & 7) << 4;

  for (int pass = 0; pass < 2; ++pass) {
    int qt = pass ? (15 - qp) : qp;
    int qrow0 = qt * 128 + w * 16;

    bf16x8 aq[4];
#pragma unroll
    for (int ks = 0; ks < 4; ++ks)
      aq[ks] = *(const bf16x8*)(q + (((size_t)b * 2048 + qrow0 + l15) * 32 + h) * 128 + ks * 32 + g * 8);

    f32x4 acco[8];
#pragma unroll
    for (int n = 0; n < 8; ++n) acco[n] = (f32x4){0.f, 0.f, 0.f, 0.f};
    float m_r[4] = {NEG, NEG, NEG, NEG};
    float l_r[4] = {0.f, 0.f, 0.f, 0.f};

    const int nk = 2 * qt + 2;
    stage(0, 0);
    stage(64, 1);
    asm volatile("s_waitcnt vmcnt(4)");
    __builtin_amdgcn_sched_barrier(0);
    __builtin_amdgcn_s_barrier();

    for (int kt = 0; kt < nk; ++kt) {
      int kv0 = kt * 64;
      int cur = kt % 3;
      if (kt + 2 < nk) stage(kv0 + 128, (kt + 2) % 3);

      if (kv0 <= qrow0 + 15) {
        f32x4 s[4];
#pragma unroll
        for (int n = 0; n < 4; ++n) s[n] = (f32x4){0.f, 0.f, 0.f, 0.f};
#pragma unroll
        for (int ks = 0; ks < 4; ++ks) {
          int off = ((ks * 64 + g * 16) ^ kxor) >> 1;
#pragma unroll
          for (int n = 0; n < 4; ++n) {
            bf16x8 kb = *(const bf16x8*)&Ks[cur][(n * 16 + l15) * 128 + off];
            s[n] = __builtin_amdgcn_mfma_f32_16x16x32_bf16(aq[ks], kb, s[n], 0, 0, 0);
          }
        }
        if (kv0 + 63 > qrow0) {
#pragma unroll
          for (int n = 0; n < 4; ++n)
#pragma unroll
            for (int r = 0; r < 4; ++r) {
              int qg = qrow0 + g * 4 + r;
              int kg = kv0 + n * 16 + l15;
              if (kg > qg) s[n][r] = NEG;
            }
        }
        float fac[4];
#pragma unroll
        for (int r = 0; r < 4; ++r) {
          float mx = fmaxf(fmaxf(s[0][r], s[1][r]), fmaxf(s[2][r], s[3][r]));
#pragma unroll
          for (int off = 1; off < 16; off <<= 1) mx = fmaxf(mx, __shfl_xor(mx, off));
          float mn = fmaxf(m_r[r], mx);
          fac[r] = exp2f((m_r[r] - mn) * C2);
          m_r[r] = mn;
        }
        float psum[4] = {0.f, 0.f, 0.f, 0.f};
#pragma unroll
        for (int n = 0; n < 4; ++n)
#pragma unroll
          for (int r = 0; r < 4; ++r) {
            float p = exp2f((s[n][r] - m_r[r]) * C2);
            psum[r] += p;
            Pw[(g * 4 + r) * 80 + n * 16 + l15] = (bf16)p;
          }
#pragma unroll
        for (int r = 0; r < 4; ++r) {
          float ps = psum[r];
#pragma unroll
          for (int off = 1; off < 16; off <<= 1) ps += __shfl_xor(ps, off);
          l_r[r] = l_r[r] * fac[r] + ps;
        }
#pragma unroll
        for (int n = 0; n < 8; ++n)
#pragma unroll
          for (int r = 0; r < 4; ++r) acco[n][r] *= fac[r];
        __builtin_amdgcn_sched_barrier(0);
        asm volatile("s_waitcnt lgkmcnt(0)");
        __builtin_amdgcn_sched_barrier(0);
#pragma unroll
        for (int ks = 0; ks < 2; ++ks) {
          bf16x8 pa = *(const bf16x8*)&Pw[l15 * 80 + ks * 32 + g * 8];
          int off = ((ks * 64 + g * 16) ^ kxor) >> 1;
#pragma unroll
          for (int n = 0; n < 8; ++n) {
            bf16x8 vb = *(const bf16x8*)&Vs[cur][(n * 16 + l15) * 64 + off];
            acco[n] = __builtin_amdgcn_mfma_f32_16x16x32_bf16(pa, vb, acco[n], 0, 0, 0);
          }
        }
      }

      if (kt + 1 < nk) {
        if (kt + 2 < nk) { asm volatile("s_waitcnt vmcnt(4)"); }
        else             { asm volatile("s_waitcnt vmcnt(0)"); }
        __builtin_amdgcn_sched_barrier(0);
      }
      __builtin_amdgcn_s_barrier();
    }

#pragma unroll
    for (int r = 0; r < 4; ++r) {
      float inv = 1.0f / l_r[r];
      int qg = qrow0 + g * 4 + r;
#pragma unroll
      for (int n = 0; n < 8; ++n)
        ctx[(((size_t)b * 2048 + qg) * 32 + h) * 128 + n * 16 + l15] = (bf16)(acco[n][r] * inv);
    }
  }
}

// ---------- launcher ----------
extern "C" void kernel_launch(void* const* d_in, const int* in_sizes, int n_in,
                              void* d_out, int out_size, void* d_ws, size_t ws_size,
                              hipStream_t stream) {
  const float* x = (const float*)d_in[0];
  const float* wqkv = (const float*)d_in[1];
  const float* wo = (const float*)d_in[2];
  float* out = (float*)d_out;
  char* ws = (char*)d_ws;

  // workspace layout (bytes); total = 185,597,952
  bf16* xbf    = (bf16*)(ws + 0);            // 33,554,432  (reused as ctx later)
  bf16* wqkvbf = (bf16*)(ws + 33554432);     // 50,331,648
  bf16* qkvbf  = (bf16*)(ws + 83886080);     // 50,331,648  (reused as wo_bf later)
  bf16* qbuf   = (bf16*)(ws + 134217728);    // 33,554,432
  bf16* kbuf   = (bf16*)(ws + 167772160);    // 8,388,608
  bf16* vtbuf  = (bf16*)(ws + 176160768);    // 8,388,608
  float2* tab  = (float2*)(ws + 184549376);  // 1,048,576

  // 1. converts + rope table
  f2bf_k<<<8192, 256, 0, stream>>>(x, xbf, M_ * E_ / 8);
  f2bf_k<<<12288, 256, 0, stream>>>(wqkv, wqkvbf, F_ * E_ / 8);
  rope_table_k<<<512, 256, 0, stream>>>(tab);

  // 2. QKV projection: qkv[M][F] = x[M][E] * wqkv[F][E]^T
  gemm256<bf16><<<dim3(M_ / 256, F_ / 256), 512, 0, stream>>>(xbf, wqkvbf, qkvbf, M_, F_, E_);

  // 3. RoPE + layout shuffles
  rope_q_k<<<8192, 256, 0, stream>>>(qkvbf, tab, qbuf);
  rope_k_k<<<2048, 256, 0, stream>>>(qkvbf, tab, kbuf);
  vtrans_k<<<2048, 256, 0, stream>>>(qkvbf, vtbuf);

  // 4. convert wo into the (now dead) qkv region
  bf16* wobf = qkvbf;
  f2bf_k<<<8192, 256, 0, stream>>>(wo, wobf, E_ * E_ / 8);

  // 5. attention -> ctx (reuses xbf region, dead after GEMM1)
  bf16* ctx = xbf;
  attn_k<<<512, 512, 0, stream>>>(qbuf, kbuf, vtbuf, ctx);

  // 6. output projection: out[M][E] = ctx[M][E] * wo[E][E]^T  (fp32 out)
  gemm256<float><<<dim3(M_ / 256, E_ / 256), 512, 0, stream>>>(ctx, wobf, out, M_, E_, E_);
}